// Round 15
// baseline (291.711 us; speedup 1.0000x reference)
//
#include <hip/hip_runtime.h>

typedef unsigned short u16;
typedef unsigned int u32;
typedef __attribute__((ext_vector_type(8))) short bf16x8;
typedef __attribute__((ext_vector_type(4))) float f32x4;
typedef __attribute__((ext_vector_type(4))) unsigned short u16x4;
typedef __attribute__((ext_vector_type(2))) unsigned short u16x2;

#define NKV 144   // 128 V-dims + 1 ones-row (Ksum) + 15 pad (9 MFMA n-frags)

__device__ __forceinline__ u16 f2b(float f){
  u32 i = __float_as_uint(f);
  u32 r = (i + 0x7FFFu + ((i >> 16) & 1u)) >> 16;
  return (u16)r;
}

__device__ __forceinline__ void cp16(const void* g, void* l){
  __builtin_amdgcn_global_load_lds(
      (__attribute__((address_space(1))) void*)(const_cast<void*>(g)),
      (__attribute__((address_space(3))) void*)(l), 16, 0, 0);
}

// Stage rows x 64 bf16 into LDS, 256 threads. Linear LDS dest; XOR 16B-chunk
// swizzle applied on the GLOBAL source (conflict-light reads, measured 0).
__device__ __forceinline__ void stage_tile(const u16* g, int stride_el, int rows,
                                           u16* lds, int tid){
  const char* gc = (const char*)g;
  char* lc = (char*)lds;
  const int total = rows * 128;
  for (int off = tid * 16; off < total; off += 4096){
    int row = off >> 7;
    int chunk = (off >> 4) & 7;
    int gchunk = chunk ^ (row & 7);
    cp16(gc + (size_t)row * (size_t)(stride_el * 2) + gchunk * 16, lc + off);
  }
}

// 512-thread stagers for the 256x256 pipelined core (global row stride 1024 el).
__device__ __forceinline__ void stage_half(const u16* gtile, int rowbase,
                                           u16* ldst, int tid){
  const char* gc = (const char*)gtile;
  char* lc = (char*)ldst;
#pragma unroll
  for (int it = 0; it < 2; ++it){
    int off = tid * 16 + it * 8192;
    int row = rowbase + (off >> 7);
    int chunk = (off >> 4) & 7;
    int gchunk = chunk ^ (row & 7);
    cp16(gc + (size_t)row * 2048 + gchunk * 16, lc + (size_t)row * 128 + chunk * 16);
  }
}
__device__ __forceinline__ void stage_aq(const u16* gtile, int q,
                                         u16* ldst, int tid){
  const char* gc = (const char*)gtile;
  char* lc = (char*)ldst;
  int rp = tid >> 3;
  int row = (rp < 32) ? (q * 32 + rp) : (128 + q * 32 + (rp - 32));
  int chunk = tid & 7;
  int gchunk = chunk ^ (row & 7);
  cp16(gc + (size_t)row * 2048 + gchunk * 16, lc + (size_t)row * 128 + chunk * 16);
}

// Fragment read: logical (row, k-chunk) -> swizzled physical chunk.
__device__ __forceinline__ bf16x8 frag_ld(const u16* lds, int row, int kk, int lane){
  int chunk = (kk >> 3) + (lane >> 4);
  int pc = chunk ^ (row & 7);
  return *(const bf16x8*)(lds + row * 64 + pc * 8);
}

__device__ __forceinline__ void ld_bfr(const u16* lB, int wc, int lane,
                                       bf16x8 (&bfr)[4][2]){
#pragma unroll
  for (int nf = 0; nf < 4; ++nf)
#pragma unroll
    for (int kk = 0; kk < 2; ++kk)
      bfr[nf][kk] = frag_ld(lB, wc * 64 + nf * 16 + (lane & 15), kk * 32, lane);
}
__device__ __forceinline__ void ld_af(const u16* lA, int q, int wr, int lane,
                                      bf16x8 (&af)[2][2]){
#pragma unroll
  for (int mi = 0; mi < 2; ++mi)
#pragma unroll
    for (int kk = 0; kk < 2; ++kk)
      af[mi][kk] = frag_ld(lA, wr * 128 + (q * 2 + mi) * 16 + (lane & 15), kk * 32, lane);
}
__device__ __forceinline__ void do_mfma(int q, bf16x8 (&af)[2][2],
                                        bf16x8 (&bfr)[4][2], f32x4 (&acc)[8][4]){
  __builtin_amdgcn_s_setprio(1);
#pragma unroll
  for (int mi = 0; mi < 2; ++mi)
#pragma unroll
    for (int nf = 0; nf < 4; ++nf)
#pragma unroll
      for (int kk = 0; kk < 2; ++kk)
        acc[q * 2 + mi][nf] = __builtin_amdgcn_mfma_f32_16x16x32_bf16(
            af[mi][kk], bfr[nf][kk], acc[q * 2 + mi][nf], 0, 0, 0);
  __builtin_amdgcn_s_setprio(0);
}

// ---- 256x256 4-phase lockstep pipelined core (verified r12; used by k_out). ----
__device__ __forceinline__ void core256p(const u16* Ag, const u16* Bg, int ksteps,
                                         u16 (*lds)[2][16384], f32x4 (&acc)[8][4]){
  const int tid = threadIdx.x, lane = tid & 63, w = tid >> 6;
  const int wr = w >> 2, wc = w & 3;
  stage_half(Bg, 0, lds[0][1], tid);
  stage_half(Bg, 128, lds[0][1], tid);
  stage_aq(Ag, 0, lds[0][0], tid);
  stage_aq(Ag, 1, lds[0][0], tid);
  stage_aq(Ag, 2, lds[0][0], tid);
  stage_aq(Ag, 3, lds[0][0], tid);
  asm volatile("s_waitcnt vmcnt(3)" ::: "memory");
  __builtin_amdgcn_sched_barrier(0);
  __builtin_amdgcn_s_barrier();
  __builtin_amdgcn_sched_barrier(0);
  for (int t = 0; t < ksteps; ++t){
    const int cur = t & 1;
    const u16* lA = lds[cur][0];
    const u16* lB = lds[cur][1];
    u16* nA = lds[cur ^ 1][0];
    u16* nB = lds[cur ^ 1][1];
    const bool pf = (t + 1 < ksteps);
    const u16* An = Ag + (t + 1) * 64;
    const u16* Bn = Bg + (t + 1) * 64;
    bf16x8 bfr[4][2], af[2][2];
    ld_bfr(lB, wc, lane, bfr);
    ld_af(lA, 0, wr, lane, af);
    if (pf) stage_half(Bn, 0, nB, tid);
    __builtin_amdgcn_s_barrier();
    asm volatile("s_waitcnt lgkmcnt(0)" ::: "memory");
    __builtin_amdgcn_sched_barrier(0);
    do_mfma(0, af, bfr, acc);
    if (pf) asm volatile("s_waitcnt vmcnt(4)" ::: "memory");
    else    asm volatile("s_waitcnt vmcnt(2)" ::: "memory");
    __builtin_amdgcn_sched_barrier(0);
    __builtin_amdgcn_s_barrier();
    __builtin_amdgcn_sched_barrier(0);
    ld_af(lA, 1, wr, lane, af);
    if (pf) stage_half(Bn, 128, nB, tid);
    __builtin_amdgcn_s_barrier();
    asm volatile("s_waitcnt lgkmcnt(0)" ::: "memory");
    __builtin_amdgcn_sched_barrier(0);
    do_mfma(1, af, bfr, acc);
    if (pf) asm volatile("s_waitcnt vmcnt(5)" ::: "memory");
    else    asm volatile("s_waitcnt vmcnt(1)" ::: "memory");
    __builtin_amdgcn_sched_barrier(0);
    __builtin_amdgcn_s_barrier();
    __builtin_amdgcn_sched_barrier(0);
    ld_af(lA, 2, wr, lane, af);
    if (pf){ stage_aq(An, 0, nA, tid); stage_aq(An, 1, nA, tid); }
    __builtin_amdgcn_s_barrier();
    asm volatile("s_waitcnt lgkmcnt(0)" ::: "memory");
    __builtin_amdgcn_sched_barrier(0);
    do_mfma(2, af, bfr, acc);
    if (pf) asm volatile("s_waitcnt vmcnt(6)" ::: "memory");
    else    asm volatile("s_waitcnt vmcnt(0)" ::: "memory");
    __builtin_amdgcn_sched_barrier(0);
    __builtin_amdgcn_s_barrier();
    __builtin_amdgcn_sched_barrier(0);
    ld_af(lA, 3, wr, lane, af);
    if (pf){ stage_aq(An, 2, nA, tid); stage_aq(An, 3, nA, tid); }
    __builtin_amdgcn_s_barrier();
    asm volatile("s_waitcnt lgkmcnt(0)" ::: "memory");
    __builtin_amdgcn_sched_barrier(0);
    do_mfma(3, af, bfr, acc);
    if (pf){
      asm volatile("s_waitcnt vmcnt(3)" ::: "memory");
    }
    __builtin_amdgcn_sched_barrier(0);
    __builtin_amdgcn_s_barrier();
    __builtin_amdgcn_sched_barrier(0);
  }
}

// ---- core A: 4 waves 2x2, 128x128 tile ----
__device__ __forceinline__ void core22(const u16* Ag, int As, const u16* Bg, int Bs,
                                       int ksteps, u16* ldsA, u16* ldsB,
                                       f32x4 (&acc)[4][4]){
  const int tid = threadIdx.x, lane = tid & 63, w = tid >> 6;
  const int wm = (w >> 1) * 64, wn = (w & 1) * 64;
  for (int t = 0; t < ksteps; ++t){
    stage_tile(Ag + t * 64, As, 128, ldsA, tid);
    stage_tile(Bg + t * 64, Bs, 128, ldsB, tid);
    __syncthreads();
#pragma unroll
    for (int kk = 0; kk < 64; kk += 32){
      bf16x8 af[4], bfr[4];
#pragma unroll
      for (int i = 0; i < 4; ++i) af[i]  = frag_ld(ldsA, wm + i * 16 + (lane & 15), kk, lane);
#pragma unroll
      for (int i = 0; i < 4; ++i) bfr[i] = frag_ld(ldsB, wn + i * 16 + (lane & 15), kk, lane);
#pragma unroll
      for (int m = 0; m < 4; ++m)
#pragma unroll
        for (int n = 0; n < 4; ++n)
          acc[m][n] = __builtin_amdgcn_mfma_f32_16x16x32_bf16(af[m], bfr[n], acc[m][n], 0, 0, 0);
    }
    __syncthreads();
  }
}

// ---- core B: 4 waves m-stacked, 128x144 (k_kv) ----
__device__ __forceinline__ void core41(const u16* Ag, int As, const u16* Bg, int Bs,
                                       int ksteps, u16* ldsA, u16* ldsB,
                                       f32x4 (&acc)[2][9]){
  const int tid = threadIdx.x, lane = tid & 63, w = tid >> 6;
  const int wm = w * 32;
  for (int t = 0; t < ksteps; ++t){
    stage_tile(Ag + t * 64, As, 128, ldsA, tid);
    stage_tile(Bg + t * 64, Bs, NKV, ldsB, tid);
    __syncthreads();
#pragma unroll
    for (int kk = 0; kk < 64; kk += 32){
      bf16x8 af[2], bfr[9];
#pragma unroll
      for (int i = 0; i < 2; ++i) af[i]  = frag_ld(ldsA, wm + i * 16 + (lane & 15), kk, lane);
#pragma unroll
      for (int i = 0; i < 9; ++i) bfr[i] = frag_ld(ldsB, i * 16 + (lane & 15), kk, lane);
#pragma unroll
      for (int m = 0; m < 2; ++m)
#pragma unroll
        for (int n = 0; n < 9; ++n)
          acc[m][n] = __builtin_amdgcn_mfma_f32_16x16x32_bf16(af[m], bfr[n], acc[m][n], 0, 0, 0);
    }
    __syncthreads();
  }
}

// ---- merged prep (unchanged from r8) ----
__global__ void k_prep(const float* __restrict__ x, u16* __restrict__ xb,
                       u16* __restrict__ VT,
                       const float* __restrict__ Wv, const float* __restrict__ Wo,
                       u16* __restrict__ WvT, u16* __restrict__ WoT,
                       const float* __restrict__ Wq, const float* __restrict__ bq,
                       const float* __restrict__ Wk, const float* __restrict__ bk,
                       const float* __restrict__ om,
                       u16* __restrict__ Wqb, u16* __restrict__ Wkb,
                       u16* __restrict__ omT, float* __restrict__ bphi){
  __shared__ float t[64][65];
  const int bid = blockIdx.x;
  const int tid = threadIdx.x;
  if (bid < 2048){
    const int n4 = 16384 * 1024 / 4;
    const int stride = 2048 * 256;
    for (int i = bid * 256 + tid; i < n4; i += stride){
      float4 v = ((const float4*)x)[i];
      u16x4 o; o[0] = f2b(v.x); o[1] = f2b(v.y); o[2] = f2b(v.z); o[3] = f2b(v.w);
      ((u16x4*)xb)[i] = o;
    }
  } else if (bid < 2304){
    const int total = 32 * 16 * 4096 / 4;
    const int stride = 256 * 256;
    for (int i = (bid - 2048) * 256 + tid; i < total; i += stride){
      int idx = i * 4;
      int s   = idx & 4095;
      int rem = idx >> 12;
      int row = 128 + (rem & 15);
      int bh  = rem >> 4;
      u16 val = (row == 128) ? (u16)0x3F80 : (u16)0;
      u16x4 o = {val, val, val, val};
      *(u16x4*)&VT[((size_t)bh * NKV + row) * 4096 + s] = o;
    }
  } else if (bid < 2816){
    const int local = bid - 2304;
    const int z = local >> 8, xy = local & 255;
    const float* src = z ? Wo : Wv;
    u16* dst = z ? WoT : WvT;
    const int c0 = (xy & 15) * 64, r0 = (xy >> 4) * 64;
    for (int i = tid; i < 4096; i += 256){
      int r = i >> 6, c = i & 63;
      t[r][c] = src[(size_t)(r0 + r) * 1024 + c0 + c];
    }
    __syncthreads();
    for (int i = tid; i < 4096; i += 256){
      int r = i >> 6, c = i & 63;
      dst[(size_t)(c0 + r) * 1024 + r0 + c] = f2b(t[c][r]);
    }
  } else if (bid < 3072){
    const int local = bid - 2816;
    const int total = 2 * 1024 * 1024 / 4;
    const int stride = 256 * 256;
    for (int i = local * 256 + tid; i < total; i += stride){
      int z = i >> 18, idx = i & 262143;
      const float4 v = ((const float4*)(z ? Wk : Wq))[idx];
      u16x4 o; o[0] = f2b(v.x); o[1] = f2b(v.y); o[2] = f2b(v.z); o[3] = f2b(v.w);
      ((u16x4*)(z ? Wkb : Wqb))[idx] = o;
    }
  } else if (bid < 3076){
    const int local = bid - 3072;
    const int f0 = (local & 1) * 64, c0 = (local >> 1) * 64;
    for (int i = tid; i < 4096; i += 256){
      int r = i >> 6, c = i & 63;
      t[r][c] = om[(size_t)(c0 + r) * 128 + f0 + c];
    }
    __syncthreads();
    for (int i = tid; i < 4096; i += 256){
      int r = i >> 6, c = i & 63;
      omT[(size_t)(f0 + r) * 128 + c0 + c] = f2b(t[c][r]);
    }
  } else {
    const int local = bid - 3076;
    const int z = local >> 2, q = local & 3;
    const int hf = q * 256 + tid;
    const int f = hf & 127, h = hf >> 7;
    const float* bb = z ? bk : bq;
    float s = 0.f;
    for (int c = 0; c < 128; ++c) s += bb[h * 128 + c] * om[c * 128 + f];
    bphi[z * 1024 + hf] = s;
  }
}

// ---- k_wf: Wphi^T via MFMA (unchanged) ----
__global__ __launch_bounds__(256, 2)
void k_wf(const u16* __restrict__ omT, const u16* __restrict__ Wqb,
          const u16* __restrict__ Wkb, u16* __restrict__ WqpT, u16* __restrict__ WkpT){
  __shared__ u16 ldsA[128 * 64];
  __shared__ u16 ldsB[128 * 64];
  const int dtile = blockIdx.x, h = blockIdx.y, z = blockIdx.z;
  const u16* Wb = z ? Wkb : Wqb;
  u16* WT = z ? WkpT : WqpT;
  const u16* Ag = omT;
  const u16* Bg = Wb + (size_t)dtile * 128 * 1024 + h * 128;
  f32x4 acc[4][4];
#pragma unroll
  for (int m = 0; m < 4; ++m)
#pragma unroll
    for (int n = 0; n < 4; ++n) acc[m][n] = f32x4{0.f, 0.f, 0.f, 0.f};
  core22(Ag, 128, Bg, 1024, 2, ldsA, ldsB, acc);

  const int tid = threadIdx.x, lane = tid & 63, w = tid >> 6;
  const int wm = (w >> 1) * 64, wn = (w & 1) * 64;
#pragma unroll
  for (int m = 0; m < 4; ++m){
    const int r0 = wm + m * 16 + ((lane >> 4) << 2);
#pragma unroll
    for (int n = 0; n < 4; ++n){
      const int col = wn + n * 16 + (lane & 15);
#pragma unroll
      for (int j = 0; j < 4; ++j)
        WT[(size_t)(h * 128 + r0 + j) * 1024 + dtile * 128 + col] = f2b(acc[m][n][j]);
    }
  }
}

// ---- K2: K-features + V only (Q fused into k_qattn). grid (128, 16) ----
__global__ __launch_bounds__(256, 2)
void k_qkv(const u16* __restrict__ xb, const u16* __restrict__ WkpT,
           const u16* __restrict__ WvT, const float* __restrict__ bphi,
           const float* __restrict__ bv, u16* __restrict__ KfT, u16* __restrict__ VT){
  __shared__ u16 ldsA[128 * 64];
  __shared__ u16 ldsB[128 * 64];
  const int mtile = blockIdx.x, ntile = blockIdx.y;
  const int isV = ntile >> 3, h = ntile & 7;
  const u16* Ag = xb + (size_t)mtile * 128 * 1024;
  const u16* WT = isV ? WvT : WkpT;
  const u16* Bg = WT + (size_t)h * 128 * 1024;
  f32x4 acc[4][4];
#pragma unroll
  for (int m = 0; m < 4; ++m)
#pragma unroll
    for (int n = 0; n < 4; ++n) acc[m][n] = f32x4{0.f, 0.f, 0.f, 0.f};
  core22(Ag, 1024, Bg, 1024, 16, ldsA, ldsB, acc);

  const int tid = threadIdx.x, lane = tid & 63, w = tid >> 6;
  const int wm = (w >> 1) * 64, wn = (w & 1) * 64;
  const int b  = (mtile * 128) >> 12;
  const int s0 = (mtile * 128) & 4095;
  const int bh = b * 8 + h;

  if (isV){
    const float* bias = bv + h * 128;
#pragma unroll
    for (int m = 0; m < 4; ++m){
      const int r0 = wm + m * 16 + ((lane >> 4) << 2);
#pragma unroll
      for (int n = 0; n < 4; ++n){
        const int col = wn + n * 16 + (lane & 15);
        const float bc = bias[col];
        u16x4 pk;
#pragma unroll
        for (int j = 0; j < 4; ++j) pk[j] = f2b(acc[m][n][j] + bc);
        *(u16x4*)&VT[((size_t)bh * NKV + col) * 4096 + s0 + r0] = pk;
      }
    }
    return;
  }

  const float* bph = bphi + 1024 + h * 128;   // K-section phi bias
#pragma unroll
  for (int m = 0; m < 4; ++m){
    const int r0 = wm + m * 16 + ((lane >> 4) << 2);
#pragma unroll
    for (int n = 0; n < 4; ++n){
      const int f = wn + n * 16 + (lane & 15);
      const float bc = bph[f];
      u16x4 ps, pc;
#pragma unroll
      for (int j = 0; j < 4; ++j){
        float sv, cv; __sincosf(acc[m][n][j] + bc, &sv, &cv);
        ps[j] = f2b(sv); pc[j] = f2b(cv);
      }
      size_t sb = (size_t)s0 + r0;
      *(u16x4*)&KfT[((size_t)bh * 256 + 2 * f)     * 4096 + sb] = ps;
      *(u16x4*)&KfT[((size_t)bh * 256 + 2 * f + 1) * 4096 + sb] = pc;
    }
  }
}

// ---- K3: KV = Kf^T V (+Ksum via ones row). grid (2, 32, 4) ----
__global__ __launch_bounds__(256, 2)
void k_kv(const u16* __restrict__ KfT, const u16* __restrict__ VT, float* __restrict__ part){
  __shared__ u16 ldsA[128 * 64];
  __shared__ u16 ldsB[NKV * 64];
  const int mtile = blockIdx.x, bh = blockIdx.y, ks = blockIdx.z;
  const u16* Ag = KfT + ((size_t)bh * 256 + mtile * 128) * 4096 + ks * 1024;
  const u16* Bg = VT + (size_t)bh * NKV * 4096 + ks * 1024;
  f32x4 acc[2][9];
#pragma unroll
  for (int m = 0; m < 2; ++m)
#pragma unroll
    for (int n = 0; n < 9; ++n) acc[m][n] = f32x4{0.f, 0.f, 0.f, 0.f};
  core41(Ag, 4096, Bg, 4096, 16, ldsA, ldsB, acc);

  const int tid = threadIdx.x, lane = tid & 63, w = tid >> 6;
#pragma unroll
  for (int m = 0; m < 2; ++m){
    const int mr = mtile * 128 + w * 32 + m * 16 + ((lane >> 4) << 2);
#pragma unroll
    for (int n = 0; n < 9; ++n){
      const int nn = n * 16 + (lane & 15);
      *(f32x4*)&part[(((size_t)ks * 32 + bh) * NKV + nn) * 256 + mr] = acc[m][n];
    }
  }
}

__global__ void k_kvred(const float* __restrict__ part, u16* __restrict__ KVT){
  const int total = 32 * NKV * 256;
  int idx = blockIdx.x * blockDim.x + threadIdx.x;
  if (idx >= total) return;
  float v = 0.f;
#pragma unroll
  for (int p = 0; p < 4; ++p) v += part[(size_t)p * total + idx];
  KVT[idx] = f2b(v);
}

// ---- K5: FUSED Qphi + attention. grid (128 mtiles, 8 heads).
// GEMM1: zp = x@Wqphi_h (K=1024, proven core22). Epilogue: sincos -> Qf tile
// in LDS (64 KB, chunk-XOR swizzled; reuses GEMM1 staging AFTER its final
// __syncthreads). GEMM2: att = Qf(LDS) @ KVT_h(global, L2-resident, per-lane
// register loads); denom from ones-row col 128.
// NOTE (r14 post-mortem): mtile is the GLOBAL row tile (0..127 spans all 4
// batches) -> att rows indexed by mtile*128 directly; b only selects KVT head
// block. Do NOT add b*4096 to the row.
__global__ __launch_bounds__(256, 2)
void k_qattn(const u16* __restrict__ xb, const u16* __restrict__ WqpT,
             const float* __restrict__ bphi, const u16* __restrict__ KVT,
             u16* __restrict__ att){
  __shared__ u16 qf[128 * 256];        // 64 KiB; [0,32K) doubles as GEMM1 staging
  u16* ldsA = qf;
  u16* ldsB = qf + 8192;
  const int mtile = blockIdx.x, h = blockIdx.y;
  const u16* Ag = xb + (size_t)mtile * 128 * 1024;
  const u16* Bg = WqpT + (size_t)h * 128 * 1024;
  f32x4 acc[4][4];
#pragma unroll
  for (int m = 0; m < 4; ++m)
#pragma unroll
    for (int n = 0; n < 4; ++n) acc[m][n] = f32x4{0.f, 0.f, 0.f, 0.f};
  core22(Ag, 1024, Bg, 1024, 16, ldsA, ldsB, acc);
  // core22 ends with __syncthreads -> staging region free; write Qf tile.

  const int tid = threadIdx.x, lane = tid & 63, w = tid >> 6;
  const int wm = (w >> 1) * 64, wn = (w & 1) * 64;
  const float* bph = bphi + h * 128;   // Q-section phi bias (z=0)
#pragma unroll
  for (int m = 0; m < 4; ++m){
    const int r0 = wm + m * 16 + ((lane >> 4) << 2);
#pragma unroll
    for (int n = 0; n < 4; ++n){
      const int f = wn + n * 16 + (lane & 15);
      const float bc = bph[f];
      const int col = 2 * f;
      const int chunk = col >> 3;
#pragma unroll
      for (int j = 0; j < 4; ++j){
        float sv, cv; __sincosf(acc[m][n][j] + bc, &sv, &cv);
        u16x2 p; p[0] = f2b(sv); p[1] = f2b(cv);
        const int row = r0 + j;
        const int pc = (chunk & 24) | ((chunk & 7) ^ (row & 7));
        *(u16x2*)&qf[row * 256 + pc * 8 + (col & 7)] = p;
      }
    }
  }
  __syncthreads();

  // GEMM2: att_tile[128 s][144 n] = qf @ KVT_h^T (K=256 in 8 chunks of 32)
  const int b = mtile >> 5;            // batch: selects KVT head block only
  const int bh = b * 8 + h;
  const u16* B2 = KVT + (size_t)bh * NKV * 256;
  const int arow = w * 32;             // 4 waves m-stacked
  f32x4 acc2[2][9];
#pragma unroll
  for (int m = 0; m < 2; ++m)
#pragma unroll
    for (int n = 0; n < 9; ++n) acc2[m][n] = f32x4{0.f, 0.f, 0.f, 0.f};
#pragma unroll
  for (int kc = 0; kc < 8; ++kc){
    bf16x8 af2[2], bfr2[9];
#pragma unroll
    for (int m = 0; m < 2; ++m){
      const int row = arow + m * 16 + (lane & 15);
      const int chunk = kc * 4 + (lane >> 4);
      const int pc = (chunk & 24) | ((chunk & 7) ^ (row & 7));
      af2[m] = *(const bf16x8*)&qf[row * 256 + pc * 8];
    }
#pragma unroll
    for (int i = 0; i < 9; ++i)
      bfr2[i] = *(const bf16x8*)&B2[(size_t)(i * 16 + (lane & 15)) * 256
                                    + kc * 32 + ((lane >> 4) << 3)];
#pragma unroll
    for (int m = 0; m < 2; ++m)
#pragma unroll
      for (int i = 0; i < 9; ++i)
        acc2[m][i] = __builtin_amdgcn_mfma_f32_16x16x32_bf16(af2[m], bfr2[i], acc2[m][i], 0, 0, 0);
  }

  // epilogue: denom (col 128 = ones-row) + divide + att write (GLOBAL row)
#pragma unroll
  for (int m = 0; m < 2; ++m){
    const int r0g = mtile * 128 + arow + m * 16 + ((lane >> 4) << 2);
    float rden[4];
#pragma unroll
    for (int j = 0; j < 4; ++j){
      float d = __shfl(acc2[m][8][j], lane & 48, 64);
      rden[j] = 1.f / (d + 1e-6f);
    }
#pragma unroll
    for (int n = 0; n < 8; ++n){
      const int dcol = n * 16 + (lane & 15);
#pragma unroll
      for (int j = 0; j < 4; ++j)
        att[(size_t)(r0g + j) * 1024 + h * 128 + dcol] = f2b(acc2[m][n][j] * rden[j]);
    }
  }
}

// ---- K6: final projection, 256x256 4-phase core (r12-verified). grid (64, 4) ----
__global__ __launch_bounds__(512, 1)
void k_out(const u16* __restrict__ att, const u16* __restrict__ WoT,
           const float* __restrict__ bo, float* __restrict__ out){
  __shared__ u16 lds[2][2][16384];
  const int tid = threadIdx.x, lane = tid & 63, w = tid >> 6;
  const int wr = w >> 2, wc = w & 3;
  const int mtile = blockIdx.x, ntile = blockIdx.y;
  const u16* Ag = att + (size_t)mtile * 256 * 1024;
  const u16* Bg = WoT + (size_t)ntile * 256 * 1024;
  f32x4 acc[8][4];
#pragma unroll
  for (int m = 0; m < 8; ++m)
#pragma unroll
    for (int n = 0; n < 4; ++n) acc[m][n] = f32x4{0.f, 0.f, 0.f, 0.f};
  core256p(Ag, Bg, 16, lds, acc);

#pragma unroll
  for (int mf = 0; mf < 8; ++mf){
    const int rg = mtile * 256 + wr * 128 + mf * 16 + ((lane >> 4) << 2);
#pragma unroll
    for (int nf = 0; nf < 4; ++nf){
      const int c = ntile * 256 + wc * 64 + nf * 16 + (lane & 15);
      const float bc = bo[c];
#pragma unroll
      for (int j = 0; j < 4; ++j)
        out[(size_t)(rg + j) * 1024 + c] = acc[mf][nf][j] + bc;
    }
  }
}

extern "C" void kernel_launch(void* const* d_in, const int* in_sizes, int n_in,
                              void* d_out, int out_size, void* d_ws, size_t ws_size,
                              hipStream_t stream){
  const float* x  = (const float*)d_in[0];
  const float* Wq = (const float*)d_in[1];
  const float* bq = (const float*)d_in[2];
  const float* Wk = (const float*)d_in[3];
  const float* bk = (const float*)d_in[4];
  const float* Wv = (const float*)d_in[5];
  const float* bv = (const float*)d_in[6];
  const float* Wo = (const float*)d_in[7];
  const float* bo = (const float*)d_in[8];
  const float* om = (const float*)d_in[9];
  float* out = (float*)d_out;
  char* ws = (char*)d_ws;

  // layout: xb lives until k_qattn; part/att in the former-Qf region.
  const size_t OFF_XB  = 0;             // 32 MiB : xb  [16384][1024] bf16
  const size_t OFF_KFT = 33554432;      // 64 MiB : KfT [32][256][4096] bf16
  const size_t OFF_PART= 100663296;     // 19 MiB : part [4][32][144][256] f32
  const size_t OFF_ATT = 121634816;     // 32 MiB : att [16384][1024] bf16
  const size_t OFF_VT  = 167772160;     // 36 MiB : VT  [32][144][4096] bf16
  const size_t OFF_KVT = 205520896;     // 2.25MiB: KVT [32][144][256] bf16
  const size_t OFF_WQP = 207880192;     // 2 MiB : WqphiT
  const size_t OFF_WKP = OFF_WQP + 2097152;
  const size_t OFF_WVT = OFF_WKP + 2097152;
  const size_t OFF_WOT = OFF_WVT + 2097152;
  const size_t OFF_BPH = OFF_WOT + 2097152;   // 8 KiB f32 bphi[2][1024]
  const size_t OFF_WQB = OFF_BPH + 8192;      // 2 MiB bf16 Wq
  const size_t OFF_WKB = OFF_WQB + 2097152;   // 2 MiB bf16 Wk
  const size_t OFF_OMT = OFF_WKB + 2097152;   // 32 KiB bf16 omT
  const size_t NEEDED  = OFF_OMT + 32768;
  if (ws_size < NEEDED) return;

  u16* xb   = (u16*)(ws + OFF_XB);
  u16* WqpT = (u16*)(ws + OFF_WQP);
  u16* WkpT = (u16*)(ws + OFF_WKP);
  u16* WvT  = (u16*)(ws + OFF_WVT);
  u16* WoT  = (u16*)(ws + OFF_WOT);
  float* bphi = (float*)(ws + OFF_BPH);
  u16* Wqb  = (u16*)(ws + OFF_WQB);
  u16* Wkb  = (u16*)(ws + OFF_WKB);
  u16* omT  = (u16*)(ws + OFF_OMT);
  u16* VT   = (u16*)(ws + OFF_VT);
  u16* KfT  = (u16*)(ws + OFF_KFT);
  float* part = (float*)(ws + OFF_PART);
  u16* KVT  = (u16*)(ws + OFF_KVT);
  u16* att  = (u16*)(ws + OFF_ATT);

  k_prep<<<dim3(3084), dim3(256), 0, stream>>>(x, xb, VT, Wv, Wo, WvT, WoT,
                                               Wq, bq, Wk, bk, om,
                                               Wqb, Wkb, omT, bphi);
  k_wf<<<dim3(8, 8, 2), dim3(256), 0, stream>>>(omT, Wqb, Wkb, WqpT, WkpT);
  k_qkv<<<dim3(128, 16), dim3(256), 0, stream>>>(xb, WkpT, WvT, bphi, bv, KfT, VT);
  k_kv<<<dim3(2, 32, 4), dim3(256), 0, stream>>>(KfT, VT, part);
  k_kvred<<<dim3(32 * NKV * 256 / 256), dim3(256), 0, stream>>>(part, KVT);
  k_qattn<<<dim3(128, 8), dim3(256), 0, stream>>>(xb, WqpT, bphi, KVT, att);
  k_out<<<dim3(64, 4), dim3(512), 0, stream>>>(att, WoT, bo, out);
}

// Round 16
// 257.050 us; speedup vs baseline: 1.1348x; 1.1348x over previous
//
#include <hip/hip_runtime.h>

typedef unsigned short u16;
typedef unsigned int u32;
typedef __attribute__((ext_vector_type(8))) short bf16x8;
typedef __attribute__((ext_vector_type(4))) float f32x4;
typedef __attribute__((ext_vector_type(4))) unsigned short u16x4;
typedef __attribute__((ext_vector_type(2))) unsigned short u16x2;

#define NKV 144   // 128 V-dims + 1 ones-row (Ksum) + 15 pad (9 MFMA n-frags)

__device__ __forceinline__ u16 f2b(float f){
  u32 i = __float_as_uint(f);
  u32 r = (i + 0x7FFFu + ((i >> 16) & 1u)) >> 16;
  return (u16)r;
}

__device__ __forceinline__ void cp16(const void* g, void* l){
  __builtin_amdgcn_global_load_lds(
      (__attribute__((address_space(1))) void*)(const_cast<void*>(g)),
      (__attribute__((address_space(3))) void*)(l), 16, 0, 0);
}

// Stage rows x 64 bf16 into LDS, 256 threads. Linear LDS dest; XOR 16B-chunk
// swizzle applied on the GLOBAL source (conflict-light reads, measured 0).
__device__ __forceinline__ void stage_tile(const u16* g, int stride_el, int rows,
                                           u16* lds, int tid){
  const char* gc = (const char*)g;
  char* lc = (char*)lds;
  const int total = rows * 128;
  for (int off = tid * 16; off < total; off += 4096){
    int row = off >> 7;
    int chunk = (off >> 4) & 7;
    int gchunk = chunk ^ (row & 7);
    cp16(gc + (size_t)row * (size_t)(stride_el * 2) + gchunk * 16, lc + off);
  }
}

// 512-thread stagers for the 256x256 pipelined core (global row stride 1024 el).
// Half-tile: rows rowbase..rowbase+127 (64 cols) = 2 cp16/thread.
__device__ __forceinline__ void stage_half(const u16* gtile, int rowbase,
                                           u16* ldst, int tid){
  const char* gc = (const char*)gtile;
  char* lc = (char*)ldst;
#pragma unroll
  for (int it = 0; it < 2; ++it){
    int off = tid * 16 + it * 8192;
    int row = rowbase + (off >> 7);
    int chunk = (off >> 4) & 7;
    int gchunk = chunk ^ (row & 7);
    cp16(gc + (size_t)row * 2048 + gchunk * 16, lc + (size_t)row * 128 + chunk * 16);
  }
}
// A-quarter q: rows {q*32..q*32+31} u {128+q*32..+31} = 1 cp16/thread.
__device__ __forceinline__ void stage_aq(const u16* gtile, int q,
                                         u16* ldst, int tid){
  const char* gc = (const char*)gtile;
  char* lc = (char*)ldst;
  int rp = tid >> 3;
  int row = (rp < 32) ? (q * 32 + rp) : (128 + q * 32 + (rp - 32));
  int chunk = tid & 7;
  int gchunk = chunk ^ (row & 7);
  cp16(gc + (size_t)row * 2048 + gchunk * 16, lc + (size_t)row * 128 + chunk * 16);
}

// Fragment read: logical (row, k-chunk) -> swizzled physical chunk.
__device__ __forceinline__ bf16x8 frag_ld(const u16* lds, int row, int kk, int lane){
  int chunk = (kk >> 3) + (lane >> 4);
  int pc = chunk ^ (row & 7);
  return *(const bf16x8*)(lds + row * 64 + pc * 8);
}

__device__ __forceinline__ void ld_bfr(const u16* lB, int wc, int lane,
                                       bf16x8 (&bfr)[4][2]){
#pragma unroll
  for (int nf = 0; nf < 4; ++nf)
#pragma unroll
    for (int kk = 0; kk < 2; ++kk)
      bfr[nf][kk] = frag_ld(lB, wc * 64 + nf * 16 + (lane & 15), kk * 32, lane);
}
__device__ __forceinline__ void ld_af(const u16* lA, int q, int wr, int lane,
                                      bf16x8 (&af)[2][2]){
#pragma unroll
  for (int mi = 0; mi < 2; ++mi)
#pragma unroll
    for (int kk = 0; kk < 2; ++kk)
      af[mi][kk] = frag_ld(lA, wr * 128 + (q * 2 + mi) * 16 + (lane & 15), kk * 32, lane);
}
__device__ __forceinline__ void do_mfma(int q, bf16x8 (&af)[2][2],
                                        bf16x8 (&bfr)[4][2], f32x4 (&acc)[8][4]){
  __builtin_amdgcn_s_setprio(1);
#pragma unroll
  for (int mi = 0; mi < 2; ++mi)
#pragma unroll
    for (int nf = 0; nf < 4; ++nf)
#pragma unroll
      for (int kk = 0; kk < 2; ++kk)
        acc[q * 2 + mi][nf] = __builtin_amdgcn_mfma_f32_16x16x32_bf16(
            af[mi][kk], bfr[nf][kk], acc[q * 2 + mi][nf], 0, 0, 0);
  __builtin_amdgcn_s_setprio(0);
}

// ---- 256x256 4-phase lockstep pipelined core.
// Sync rule (r10 NaN post-mortem): vmcnt is PER-WAVE; data loaded by other
// waves' global_load_lds is visible only after {their vmcnt -> barrier}. So
// every phase certifies the NEXT phase's reads via {MFMA; vmcnt(N); s_barrier}
// at its tail. Per-wave FIFO ledger (loads/tile: B0=2,B1=2,A0..A3=1 each;
// issue P0:B0n P1:B1n P2:A0n,A1n P3:A2n,A3n):
//  entry: 3 outstanding (A1,A2,A3)     [prologue vmcnt(3)+barrier]
//  P0 rd B+A0, iss B0n ->5, tail vmcnt(4) lands A1
//  P1 rd A1,   iss B1n ->6, tail vmcnt(5) lands A2
//  P2 rd A2,   iss A0n,A1n ->7, tail vmcnt(6) lands A3
//  P3 rd A3,   iss A2n,A3n ->8, tail vmcnt(3) lands B0n,B1n,A0n (invariant)
// Last iter (no prefetch): tails (2,1,0,-). Never drains mid-loop.
__device__ __forceinline__ void core256p(const u16* Ag, const u16* Bg, int ksteps,
                                         u16 (*lds)[2][16384], f32x4 (&acc)[8][4]){
  const int tid = threadIdx.x, lane = tid & 63, w = tid >> 6;
  const int wr = w >> 2, wc = w & 3;
  stage_half(Bg, 0, lds[0][1], tid);
  stage_half(Bg, 128, lds[0][1], tid);
  stage_aq(Ag, 0, lds[0][0], tid);
  stage_aq(Ag, 1, lds[0][0], tid);
  stage_aq(Ag, 2, lds[0][0], tid);
  stage_aq(Ag, 3, lds[0][0], tid);
  asm volatile("s_waitcnt vmcnt(3)" ::: "memory");
  __builtin_amdgcn_sched_barrier(0);
  __builtin_amdgcn_s_barrier();
  __builtin_amdgcn_sched_barrier(0);
  for (int t = 0; t < ksteps; ++t){
    const int cur = t & 1;
    const u16* lA = lds[cur][0];
    const u16* lB = lds[cur][1];
    u16* nA = lds[cur ^ 1][0];
    u16* nB = lds[cur ^ 1][1];
    const bool pf = (t + 1 < ksteps);
    const u16* An = Ag + (t + 1) * 64;
    const u16* Bn = Bg + (t + 1) * 64;
    bf16x8 bfr[4][2], af[2][2];
    // ---- phase 0: reads B(t), A0(t) ----
    ld_bfr(lB, wc, lane, bfr);
    ld_af(lA, 0, wr, lane, af);
    if (pf) stage_half(Bn, 0, nB, tid);
    __builtin_amdgcn_s_barrier();
    asm volatile("s_waitcnt lgkmcnt(0)" ::: "memory");
    __builtin_amdgcn_sched_barrier(0);
    do_mfma(0, af, bfr, acc);
    if (pf) asm volatile("s_waitcnt vmcnt(4)" ::: "memory");
    else    asm volatile("s_waitcnt vmcnt(2)" ::: "memory");
    __builtin_amdgcn_sched_barrier(0);
    __builtin_amdgcn_s_barrier();
    __builtin_amdgcn_sched_barrier(0);
    // ---- phase 1: reads A1(t) ----
    ld_af(lA, 1, wr, lane, af);
    if (pf) stage_half(Bn, 128, nB, tid);
    __builtin_amdgcn_s_barrier();
    asm volatile("s_waitcnt lgkmcnt(0)" ::: "memory");
    __builtin_amdgcn_sched_barrier(0);
    do_mfma(1, af, bfr, acc);
    if (pf) asm volatile("s_waitcnt vmcnt(5)" ::: "memory");
    else    asm volatile("s_waitcnt vmcnt(1)" ::: "memory");
    __builtin_amdgcn_sched_barrier(0);
    __builtin_amdgcn_s_barrier();
    __builtin_amdgcn_sched_barrier(0);
    // ---- phase 2: reads A2(t) ----
    ld_af(lA, 2, wr, lane, af);
    if (pf){ stage_aq(An, 0, nA, tid); stage_aq(An, 1, nA, tid); }
    __builtin_amdgcn_s_barrier();
    asm volatile("s_waitcnt lgkmcnt(0)" ::: "memory");
    __builtin_amdgcn_sched_barrier(0);
    do_mfma(2, af, bfr, acc);
    if (pf) asm volatile("s_waitcnt vmcnt(6)" ::: "memory");
    else    asm volatile("s_waitcnt vmcnt(0)" ::: "memory");
    __builtin_amdgcn_sched_barrier(0);
    __builtin_amdgcn_s_barrier();
    __builtin_amdgcn_sched_barrier(0);
    // ---- phase 3: reads A3(t) ----
    ld_af(lA, 3, wr, lane, af);
    if (pf){ stage_aq(An, 2, nA, tid); stage_aq(An, 3, nA, tid); }
    __builtin_amdgcn_s_barrier();
    asm volatile("s_waitcnt lgkmcnt(0)" ::: "memory");
    __builtin_amdgcn_sched_barrier(0);
    do_mfma(3, af, bfr, acc);
    if (pf){
      asm volatile("s_waitcnt vmcnt(3)" ::: "memory");
    }
    __builtin_amdgcn_sched_barrier(0);
    __builtin_amdgcn_s_barrier();
    __builtin_amdgcn_sched_barrier(0);
  }
}

// ---- core A: 4 waves 2x2, 128x128 tile (k_wf only) ----
__device__ __forceinline__ void core22(const u16* Ag, int As, const u16* Bg, int Bs,
                                       int ksteps, u16* ldsA, u16* ldsB,
                                       f32x4 (&acc)[4][4]){
  const int tid = threadIdx.x, lane = tid & 63, w = tid >> 6;
  const int wm = (w >> 1) * 64, wn = (w & 1) * 64;
  for (int t = 0; t < ksteps; ++t){
    stage_tile(Ag + t * 64, As, 128, ldsA, tid);
    stage_tile(Bg + t * 64, Bs, 128, ldsB, tid);
    __syncthreads();
#pragma unroll
    for (int kk = 0; kk < 64; kk += 32){
      bf16x8 af[4], bfr[4];
#pragma unroll
      for (int i = 0; i < 4; ++i) af[i]  = frag_ld(ldsA, wm + i * 16 + (lane & 15), kk, lane);
#pragma unroll
      for (int i = 0; i < 4; ++i) bfr[i] = frag_ld(ldsB, wn + i * 16 + (lane & 15), kk, lane);
#pragma unroll
      for (int m = 0; m < 4; ++m)
#pragma unroll
        for (int n = 0; n < 4; ++n)
          acc[m][n] = __builtin_amdgcn_mfma_f32_16x16x32_bf16(af[m], bfr[n], acc[m][n], 0, 0, 0);
    }
    __syncthreads();
  }
}

// ---- core B: 4 waves m-stacked, 128x144 (k_kv, k_attn) ----
__device__ __forceinline__ void core41(const u16* Ag, int As, const u16* Bg, int Bs,
                                       int ksteps, u16* ldsA, u16* ldsB,
                                       f32x4 (&acc)[2][9]){
  const int tid = threadIdx.x, lane = tid & 63, w = tid >> 6;
  const int wm = w * 32;
  for (int t = 0; t < ksteps; ++t){
    stage_tile(Ag + t * 64, As, 128, ldsA, tid);
    stage_tile(Bg + t * 64, Bs, NKV, ldsB, tid);
    __syncthreads();
#pragma unroll
    for (int kk = 0; kk < 64; kk += 32){
      bf16x8 af[2], bfr[9];
#pragma unroll
      for (int i = 0; i < 2; ++i) af[i]  = frag_ld(ldsA, wm + i * 16 + (lane & 15), kk, lane);
#pragma unroll
      for (int i = 0; i < 9; ++i) bfr[i] = frag_ld(ldsB, i * 16 + (lane & 15), kk, lane);
#pragma unroll
      for (int m = 0; m < 2; ++m)
#pragma unroll
        for (int n = 0; n < 9; ++n)
          acc[m][n] = __builtin_amdgcn_mfma_f32_16x16x32_bf16(af[m], bfr[n], acc[m][n], 0, 0, 0);
    }
    __syncthreads();
  }
}

// ---- merged prep (unchanged from r8) ----
__global__ void k_prep(const float* __restrict__ x, u16* __restrict__ xb,
                       u16* __restrict__ VT,
                       const float* __restrict__ Wv, const float* __restrict__ Wo,
                       u16* __restrict__ WvT, u16* __restrict__ WoT,
                       const float* __restrict__ Wq, const float* __restrict__ bq,
                       const float* __restrict__ Wk, const float* __restrict__ bk,
                       const float* __restrict__ om,
                       u16* __restrict__ Wqb, u16* __restrict__ Wkb,
                       u16* __restrict__ omT, float* __restrict__ bphi){
  __shared__ float t[64][65];
  const int bid = blockIdx.x;
  const int tid = threadIdx.x;
  if (bid < 2048){
    const int n4 = 16384 * 1024 / 4;
    const int stride = 2048 * 256;
    for (int i = bid * 256 + tid; i < n4; i += stride){
      float4 v = ((const float4*)x)[i];
      u16x4 o; o[0] = f2b(v.x); o[1] = f2b(v.y); o[2] = f2b(v.z); o[3] = f2b(v.w);
      ((u16x4*)xb)[i] = o;
    }
  } else if (bid < 2304){
    const int total = 32 * 16 * 4096 / 4;
    const int stride = 256 * 256;
    for (int i = (bid - 2048) * 256 + tid; i < total; i += stride){
      int idx = i * 4;
      int s   = idx & 4095;
      int rem = idx >> 12;
      int row = 128 + (rem & 15);
      int bh  = rem >> 4;
      u16 val = (row == 128) ? (u16)0x3F80 : (u16)0;
      u16x4 o = {val, val, val, val};
      *(u16x4*)&VT[((size_t)bh * NKV + row) * 4096 + s] = o;
    }
  } else if (bid < 2816){
    const int local = bid - 2304;
    const int z = local >> 8, xy = local & 255;
    const float* src = z ? Wo : Wv;
    u16* dst = z ? WoT : WvT;
    const int c0 = (xy & 15) * 64, r0 = (xy >> 4) * 64;
    for (int i = tid; i < 4096; i += 256){
      int r = i >> 6, c = i & 63;
      t[r][c] = src[(size_t)(r0 + r) * 1024 + c0 + c];
    }
    __syncthreads();
    for (int i = tid; i < 4096; i += 256){
      int r = i >> 6, c = i & 63;
      dst[(size_t)(c0 + r) * 1024 + r0 + c] = f2b(t[c][r]);
    }
  } else if (bid < 3072){
    const int local = bid - 2816;
    const int total = 2 * 1024 * 1024 / 4;
    const int stride = 256 * 256;
    for (int i = local * 256 + tid; i < total; i += stride){
      int z = i >> 18, idx = i & 262143;
      const float4 v = ((const float4*)(z ? Wk : Wq))[idx];
      u16x4 o; o[0] = f2b(v.x); o[1] = f2b(v.y); o[2] = f2b(v.z); o[3] = f2b(v.w);
      ((u16x4*)(z ? Wkb : Wqb))[idx] = o;
    }
  } else if (bid < 3076){
    const int local = bid - 3072;
    const int f0 = (local & 1) * 64, c0 = (local >> 1) * 64;
    for (int i = tid; i < 4096; i += 256){
      int r = i >> 6, c = i & 63;
      t[r][c] = om[(size_t)(c0 + r) * 128 + f0 + c];
    }
    __syncthreads();
    for (int i = tid; i < 4096; i += 256){
      int r = i >> 6, c = i & 63;
      omT[(size_t)(f0 + r) * 128 + c0 + c] = f2b(t[c][r]);
    }
  } else {
    const int local = bid - 3076;
    const int z = local >> 2, q = local & 3;
    const int hf = q * 256 + tid;
    const int f = hf & 127, h = hf >> 7;
    const float* bb = z ? bk : bq;
    float s = 0.f;
    for (int c = 0; c < 128; ++c) s += bb[h * 128 + c] * om[c * 128 + f];
    bphi[z * 1024 + hf] = s;
  }
}

// ---- k_wf: Wphi^T via MFMA (unchanged) ----
__global__ __launch_bounds__(256, 2)
void k_wf(const u16* __restrict__ omT, const u16* __restrict__ Wqb,
          const u16* __restrict__ Wkb, u16* __restrict__ WqpT, u16* __restrict__ WkpT){
  __shared__ u16 ldsA[128 * 64];
  __shared__ u16 ldsB[128 * 64];
  const int dtile = blockIdx.x, h = blockIdx.y, z = blockIdx.z;
  const u16* Wb = z ? Wkb : Wqb;
  u16* WT = z ? WkpT : WqpT;
  const u16* Ag = omT;
  const u16* Bg = Wb + (size_t)dtile * 128 * 1024 + h * 128;
  f32x4 acc[4][4];
#pragma unroll
  for (int m = 0; m < 4; ++m)
#pragma unroll
    for (int n = 0; n < 4; ++n) acc[m][n] = f32x4{0.f, 0.f, 0.f, 0.f};
  core22(Ag, 128, Bg, 1024, 2, ldsA, ldsB, acc);

  const int tid = threadIdx.x, lane = tid & 63, w = tid >> 6;
  const int wm = (w >> 1) * 64, wn = (w & 1) * 64;
#pragma unroll
  for (int m = 0; m < 4; ++m){
    const int r0 = wm + m * 16 + ((lane >> 4) << 2);
#pragma unroll
    for (int n = 0; n < 4; ++n){
      const int col = wn + n * 16 + (lane & 15);
#pragma unroll
      for (int j = 0; j < 4; ++j)
        WT[(size_t)(h * 128 + r0 + j) * 1024 + dtile * 128 + col] = f2b(acc[m][n][j]);
    }
  }
}

// ---- K2: fused-weight QKV, 256x256 4-phase core. grid (64, 12), natural
// dispatch (XCD x -> mtiles = x mod 8 -> L2-resident A slice; no swizzle).
__global__ __launch_bounds__(512, 1)
void k_qkv(const u16* __restrict__ xb, const u16* __restrict__ WqpT,
           const u16* __restrict__ WkpT, const u16* __restrict__ WvT,
           const float* __restrict__ bphi, const float* __restrict__ bv,
           u16* __restrict__ Qf, u16* __restrict__ KfT, u16* __restrict__ VT){
  __shared__ u16 lds[2][2][16384];   // 128 KiB
  const int tid = threadIdx.x, lane = tid & 63, w = tid >> 6;
  const int wr = w >> 2, wc = w & 3;
  const int mtile = blockIdx.x, ntile = blockIdx.y;
  const int sect = ntile >> 2;
  const u16* WT = sect == 0 ? WqpT : (sect == 1 ? WkpT : WvT);
  const u16* Ag = xb + (size_t)mtile * 256 * 1024;
  const u16* Bg = WT + (size_t)(ntile & 3) * 256 * 1024;
  f32x4 acc[8][4];
#pragma unroll
  for (int m = 0; m < 8; ++m)
#pragma unroll
    for (int n = 0; n < 4; ++n) acc[m][n] = f32x4{0.f, 0.f, 0.f, 0.f};
  core256p(Ag, Bg, 16, lds, acc);

  const int b  = mtile >> 4;
  const int s0 = (mtile & 15) * 256;
  const int srow = wr * 128 + ((lane >> 4) << 2);
  const int pos  = wc * 64 + (lane & 15);
  const int gws  = (ntile & 3) * 256;

  if (sect == 2){
#pragma unroll
    for (int mf = 0; mf < 8; ++mf){
      const int sr = s0 + srow + mf * 16;
#pragma unroll
      for (int nf = 0; nf < 4; ++nf){
        const int gw = gws + pos + nf * 16;
        const int h = gw >> 7, col = gw & 127;
        const int bh = b * 8 + h;
        const float bc = bv[gw];
        u16x4 pk;
#pragma unroll
        for (int j = 0; j < 4; ++j) pk[j] = f2b(acc[mf][nf][j] + bc);
        *(u16x4*)&VT[((size_t)bh * NKV + col) * 4096 + sr] = pk;
      }
    }
    return;
  }

  const float* bps = bphi + sect * 1024;
#pragma unroll
  for (int mf = 0; mf < 8; ++mf){
    const int sr = s0 + srow + mf * 16;
#pragma unroll
    for (int nf = 0; nf < 4; ++nf){
      const int gw = gws + pos + nf * 16;
      const int h = gw >> 7, f = gw & 127;
      const int bh = b * 8 + h;
      const float bc = bps[gw];
      if (sect == 0){
#pragma unroll
        for (int j = 0; j < 4; ++j){
          float sv, cv; __sincosf(acc[mf][nf][j] + bc, &sv, &cv);
          u16x2 p; p[0] = f2b(sv); p[1] = f2b(cv);
          *(u16x2*)&Qf[((size_t)bh * 4096 + sr + j) * 256 + 2 * f] = p;
        }
      } else {
        u16x4 ps, pc;
#pragma unroll
        for (int j = 0; j < 4; ++j){
          float sv, cv; __sincosf(acc[mf][nf][j] + bc, &sv, &cv);
          ps[j] = f2b(sv); pc[j] = f2b(cv);
        }
        *(u16x4*)&KfT[((size_t)bh * 256 + 2 * f)     * 4096 + sr] = ps;
        *(u16x4*)&KfT[((size_t)bh * 256 + 2 * f + 1) * 4096 + sr] = pc;
      }
    }
  }
}

// ---- K3: KV = Kf^T V (+Ksum via ones row). grid (2, 32, 4) ----
__global__ __launch_bounds__(256, 2)
void k_kv(const u16* __restrict__ KfT, const u16* __restrict__ VT, float* __restrict__ part){
  __shared__ u16 ldsA[128 * 64];
  __shared__ u16 ldsB[NKV * 64];
  const int mtile = blockIdx.x, bh = blockIdx.y, ks = blockIdx.z;
  const u16* Ag = KfT + ((size_t)bh * 256 + mtile * 128) * 4096 + ks * 1024;
  const u16* Bg = VT + (size_t)bh * NKV * 4096 + ks * 1024;
  f32x4 acc[2][9];
#pragma unroll
  for (int m = 0; m < 2; ++m)
#pragma unroll
    for (int n = 0; n < 9; ++n) acc[m][n] = f32x4{0.f, 0.f, 0.f, 0.f};
  core41(Ag, 4096, Bg, 4096, 16, ldsA, ldsB, acc);

  const int tid = threadIdx.x, lane = tid & 63, w = tid >> 6;
#pragma unroll
  for (int m = 0; m < 2; ++m){
    const int mr = mtile * 128 + w * 32 + m * 16 + ((lane >> 4) << 2);
#pragma unroll
    for (int n = 0; n < 9; ++n){
      const int nn = n * 16 + (lane & 15);
      *(f32x4*)&part[(((size_t)ks * 32 + bh) * NKV + nn) * 256 + mr] = acc[m][n];
    }
  }
}

__global__ void k_kvred(const float* __restrict__ part, u16* __restrict__ KVT){
  const int total = 32 * NKV * 256;
  int idx = blockIdx.x * blockDim.x + threadIdx.x;
  if (idx >= total) return;
  float v = 0.f;
#pragma unroll
  for (int p = 0; p < 4; ++p) v += part[(size_t)p * total + idx];
  KVT[idx] = f2b(v);
}

// ---- K5: out = (Qf @ KV) / denom. grid (32, 32) ----
__global__ __launch_bounds__(256, 2)
void k_attn(const u16* __restrict__ Qf, const u16* __restrict__ KVT, u16* __restrict__ att){
  __shared__ u16 ldsA[128 * 64];
  __shared__ u16 ldsB[NKV * 64];
  const int mtile = blockIdx.x, bh = blockIdx.y;
  const u16* Ag = Qf + ((size_t)bh * 4096 + mtile * 128) * 256;
  const u16* Bg = KVT + (size_t)bh * NKV * 256;
  f32x4 acc[2][9];
#pragma unroll
  for (int m = 0; m < 2; ++m)
#pragma unroll
    for (int n = 0; n < 9; ++n) acc[m][n] = f32x4{0.f, 0.f, 0.f, 0.f};
  core41(Ag, 256, Bg, 256, 4, ldsA, ldsB, acc);

  const int tid = threadIdx.x, lane = tid & 63, w = tid >> 6;
  const int b = bh >> 3, h = bh & 7;
#pragma unroll
  for (int m = 0; m < 2; ++m){
    const int r0 = mtile * 128 + w * 32 + m * 16 + ((lane >> 4) << 2);
    float rden[4];
#pragma unroll
    for (int j = 0; j < 4; ++j){
      float d = __shfl(acc[m][8][j], lane & 48, 64);
      rden[j] = 1.f / (d + 1e-6f);
    }
#pragma unroll
    for (int n = 0; n < 8; ++n){
      const int dcol = n * 16 + (lane & 15);
#pragma unroll
      for (int j = 0; j < 4; ++j)
        att[((size_t)b * 4096 + r0 + j) * 1024 + h * 128 + dcol] = f2b(acc[m][n][j] * rden[j]);
    }
  }
}

// ---- K6: final projection, 256x256 4-phase core. grid (64, 4) ----
__global__ __launch_bounds__(512, 1)
void k_out(const u16* __restrict__ att, const u16* __restrict__ WoT,
           const float* __restrict__ bo, float* __restrict__ out){
  __shared__ u16 lds[2][2][16384];
  const int tid = threadIdx.x, lane = tid & 63, w = tid >> 6;
  const int wr = w >> 2, wc = w & 3;
  const int mtile = blockIdx.x, ntile = blockIdx.y;
  const u16* Ag = att + (size_t)mtile * 256 * 1024;
  const u16* Bg = WoT + (size_t)ntile * 256 * 1024;
  f32x4 acc[8][4];
#pragma unroll
  for (int m = 0; m < 8; ++m)
#pragma unroll
    for (int n = 0; n < 4; ++n) acc[m][n] = f32x4{0.f, 0.f, 0.f, 0.f};
  core256p(Ag, Bg, 16, lds, acc);

#pragma unroll
  for (int mf = 0; mf < 8; ++mf){
    const int rg = mtile * 256 + wr * 128 + mf * 16 + ((lane >> 4) << 2);
#pragma unroll
    for (int nf = 0; nf < 4; ++nf){
      const int c = ntile * 256 + wc * 64 + nf * 16 + (lane & 15);
      const float bc = bo[c];
#pragma unroll
      for (int j = 0; j < 4; ++j)
        out[(size_t)(rg + j) * 1024 + c] = acc[mf][nf][j] + bc;
    }
  }
}

extern "C" void kernel_launch(void* const* d_in, const int* in_sizes, int n_in,
                              void* d_out, int out_size, void* d_ws, size_t ws_size,
                              hipStream_t stream){
  const float* x  = (const float*)d_in[0];
  const float* Wq = (const float*)d_in[1];
  const float* bq = (const float*)d_in[2];
  const float* Wk = (const float*)d_in[3];
  const float* bk = (const float*)d_in[4];
  const float* Wv = (const float*)d_in[5];
  const float* bv = (const float*)d_in[6];
  const float* Wo = (const float*)d_in[7];
  const float* bo = (const float*)d_in[8];
  const float* om = (const float*)d_in[9];
  float* out = (float*)d_out;
  char* ws = (char*)d_ws;

  const size_t OFF_XB  = 0;             // 32 MiB : xb  [16384][1024] bf16
  const size_t OFF_PART= 0;             // 19 MiB : part (alias)
  const size_t OFF_ATT = 0;             // 32 MiB : att (alias)
  const size_t OFF_KFT = 33554432;      // 64 MiB : KfT [32][256][4096] bf16
  const size_t OFF_QF  = 100663296;     // 64 MiB : Qf  [32][4096][256] bf16
  const size_t OFF_VT  = 167772160;     // 36 MiB : VT  [32][144][4096] bf16
  const size_t OFF_KVT = 205520896;     // 2.25MiB: KVT [32][144][256] bf16
  const size_t OFF_WQP = 207880192;     // 2 MiB : WqphiT
  const size_t OFF_WKP = OFF_WQP + 2097152;
  const size_t OFF_WVT = OFF_WKP + 2097152;
  const size_t OFF_WOT = OFF_WVT + 2097152;
  const size_t OFF_BPH = OFF_WOT + 2097152;   // 8 KiB f32 bphi[2][1024]
  const size_t OFF_WQB = OFF_BPH + 8192;      // 2 MiB bf16 Wq
  const size_t OFF_WKB = OFF_WQB + 2097152;   // 2 MiB bf16 Wk
  const size_t OFF_OMT = OFF_WKB + 2097152;   // 32 KiB bf16 omT
  const size_t NEEDED  = OFF_OMT + 32768;
  if (ws_size < NEEDED) return;

  u16* xb   = (u16*)(ws + OFF_XB);
  u16* WqpT = (u16*)(ws + OFF_WQP);
  u16* WkpT = (u16*)(ws + OFF_WKP);
  u16* WvT  = (u16*)(ws + OFF_WVT);
  u16* WoT  = (u16*)(ws + OFF_WOT);
  float* bphi = (float*)(ws + OFF_BPH);
  u16* Wqb  = (u16*)(ws + OFF_WQB);
  u16* Wkb  = (u16*)(ws + OFF_WKB);
  u16* omT  = (u16*)(ws + OFF_OMT);
  u16* VT   = (u16*)(ws + OFF_VT);
  u16* Qf   = (u16*)(ws + OFF_QF);
  u16* KfT  = (u16*)(ws + OFF_KFT);
  float* part = (float*)(ws + OFF_PART);
  u16* KVT  = (u16*)(ws + OFF_KVT);
  u16* att  = (u16*)(ws + OFF_ATT);

  k_prep<<<dim3(3084), dim3(256), 0, stream>>>(x, xb, VT, Wv, Wo, WvT, WoT,
                                               Wq, bq, Wk, bk, om,
                                               Wqb, Wkb, omT, bphi);
  k_wf<<<dim3(8, 8, 2), dim3(256), 0, stream>>>(omT, Wqb, Wkb, WqpT, WkpT);
  k_qkv<<<dim3(64, 12), dim3(512), 0, stream>>>(xb, WqpT, WkpT, WvT, bphi, bv, Qf, KfT, VT);
  k_kv<<<dim3(2, 32, 4), dim3(256), 0, stream>>>(KfT, VT, part);
  k_kvred<<<dim3(32 * NKV * 256 / 256), dim3(256), 0, stream>>>(part, KVT);
  k_attn<<<dim3(32, 32), dim3(256), 0, stream>>>(Qf, KVT, att);
  k_out<<<dim3(64, 4), dim3(512), 0, stream>>>(att, WoT, bo, out);
}